// Round 1
// baseline (7151.661 us; speedup 1.0000x reference)
//
#include <hip/hip_runtime.h>
#include <hip/hip_bf16.h>

// GRU: L=2, B=32, T=1024, H=512, OUT=512
// Strategy:
//   k0: prep (zero flags, convert W_ih0 -> f16, h0 -> f16 inits)
//   k1: gx0[t][b][3H] = x[b][t][:] @ W_ih0^T + b_ih0   (parallel MFMA GEMM, f16 out)
//   k2: persistent recurrence. 48 WGs:
//       WG 0..15  (A role): layer 0, 32 hidden units each, W_hh0 slice in LDS
//       WG 16..47 (B role): layer 1, 16 hidden units each, W_ih1+W_hh1 slices in LDS
//       per-step cross-WG sync via per-t flag counters (sc1 atomics @ coherent point)
//   k3: FC on final h1 (f32)

typedef _Float16 f16x8 __attribute__((ext_vector_type(8)));
typedef float f32x4 __attribute__((ext_vector_type(4)));
typedef unsigned short u16;
typedef unsigned int u32;

#define MFMA16(a,b,c) __builtin_amdgcn_mfma_f32_16x16x32_f16((a),(b),(c),0,0,0)

static constexpr int B = 32, T = 1024, H = 512, G3 = 1536;

// ws layout (bytes)
static constexpr size_t OFF_GX0   = 0;                                  // T*B*G3*2 = 96MB
static constexpr size_t OFF_H0ALL = OFF_GX0   + (size_t)T*B*G3*2;       // 32MB
static constexpr size_t OFF_H1ALL = OFF_H0ALL + (size_t)T*B*H*2;        // 32MB
static constexpr size_t OFF_WIH0  = OFF_H1ALL + (size_t)T*B*H*2;        // 1.5MB
static constexpr size_t OFF_H0I   = OFF_WIH0  + (size_t)G3*H*2;
static constexpr size_t OFF_H1I   = OFF_H0I   + (size_t)B*H*2;
static constexpr size_t OFF_H1F   = OFF_H1I   + (size_t)B*H*2;          // f32
static constexpr size_t OFF_FLG   = OFF_H1F   + (size_t)B*H*4;          // doneA[1024], doneB[1024]

__device__ __forceinline__ u16 f2h(float x){ _Float16 h=(_Float16)x; return __builtin_bit_cast(u16,h); }
__device__ __forceinline__ float h2f(u16 u){ _Float16 h=__builtin_bit_cast(_Float16,u); return (float)h; }

// coherent (device-scope, bypass L1/L2) primitives for cross-XCD sync
__device__ __forceinline__ u32 coh_load_u32(const u32* p){
  u32 r;
  asm volatile("global_load_dword %0, %1, off sc0 sc1\n\ts_waitcnt vmcnt(0)"
               : "=v"(r) : "v"(p) : "memory");
  return r;
}
__device__ __forceinline__ void coh_store_u16(u16* p, u32 v){
  asm volatile("global_store_short %0, %1, off sc0 sc1" :: "v"(p), "v"(v) : "memory");
}
__device__ __forceinline__ void coh_atomic_inc(u32* p){
  u32 one = 1;
  asm volatile("global_atomic_add %0, %1, off sc1" :: "v"(p), "v"(one) : "memory");
}
__device__ __forceinline__ void spin_ge(const u32* p, u32 target){
  while (coh_load_u32(p) < target) { __builtin_amdgcn_s_sleep(1); }
}

__device__ __forceinline__ float fsig(float x){ return 1.f/(1.f+__expf(-x)); }
__device__ __forceinline__ float ftanh(float x){
  x = fminf(15.f, fmaxf(-15.f, x));
  float e = __expf(-2.f*x);
  return (1.f-e)/(1.f+e);
}

// MFMA B-operand fragment from XOR-swizzled LDS weights [96 rows][512] f16
__device__ __forceinline__ f16x8 lds_frag(const u16* wlds, int lrbase, int l15, int lk, int kk){
  int lr = lrbase + l15;
  int byte = lr*1024 + (((((kk<<5)+(lk<<3))<<1)) ^ ((lr&7)<<4));
  return *(const f16x8*)((const char*)wlds + byte);
}

// ---------------- k0: prep ----------------
__global__ __launch_bounds__(256) void k0_prep(const float* __restrict__ wih,
                                               const float* __restrict__ h0in,
                                               u16* __restrict__ wih0f16,
                                               u16* __restrict__ h0i,
                                               u16* __restrict__ h1i,
                                               u32* __restrict__ flags){
  int i = blockIdx.x*256 + threadIdx.x;                   // 65536 threads
  for (int idx=i; idx < G3*H; idx += 65536) wih0f16[idx] = f2h(wih[idx]);
  if (i < 2048) flags[i] = 0;
  if (i < B*H){ h0i[i] = f2h(h0in[i]); h1i[i] = f2h(h0in[B*H + i]); }
}

// ---------------- k1: gx0 GEMM ----------------
__global__ __launch_bounds__(256) void k1_gx(const float* __restrict__ x,
                                             const u16* __restrict__ wih0,
                                             const float* __restrict__ bih0,
                                             u16* __restrict__ gx0){
  int t  = blockIdx.x / 6, nb = blockIdx.x % 6;
  int wave = threadIdx.x >> 6, lane = threadIdx.x & 63;
  int l15 = lane & 15, lk = lane >> 4;
  int colbase = nb*256 + wave*64;
  f32x4 acc[2][4] = {};
#pragma unroll 4
  for (int kk=0; kk<16; kk++){
    int k0 = kk*32 + lk*8;
    f16x8 a[2];
#pragma unroll
    for (int bm=0; bm<2; bm++){
      const f32x4* xp = (const f32x4*)(x + ((size_t)(bm*16+l15)*T + t)*H + k0);
      f32x4 x0 = xp[0], x1 = xp[1];
      f16x8 v;
#pragma unroll
      for (int q=0;q<4;q++){ v[q] = (_Float16)x0[q]; v[4+q] = (_Float16)x1[q]; }
      a[bm] = v;
    }
#pragma unroll
    for (int nt=0; nt<4; nt++){
      int col = colbase + nt*16 + l15;
      f16x8 bf = *(const f16x8*)(wih0 + (size_t)col*H + k0);
      acc[0][nt] = MFMA16(a[0], bf, acc[0][nt]);
      acc[1][nt] = MFMA16(a[1], bf, acc[1][nt]);
    }
  }
#pragma unroll
  for (int nt=0; nt<4; nt++){
    int col = colbase + nt*16 + l15;
    float bias = bih0[col];
#pragma unroll
    for (int bm=0; bm<2; bm++)
#pragma unroll
      for (int j=0; j<4; j++){
        int b = bm*16 + lk*4 + j;
        gx0[((size_t)t*B + b)*G3 + col] = f2h(acc[bm][nt][j] + bias);
      }
  }
}

// ---------------- k2: persistent recurrence ----------------
__global__ __launch_bounds__(256) void k2_recur(const float* __restrict__ h0in,
                                                const float* __restrict__ Wih,
                                                const float* __restrict__ bih,
                                                const float* __restrict__ Whh,
                                                const float* __restrict__ bhh,
                                                const u16* __restrict__ gx0,
                                                u16* __restrict__ h0all,
                                                u16* __restrict__ h1all,
                                                const u16* __restrict__ h0i,
                                                const u16* __restrict__ h1i,
                                                float* __restrict__ h1fin,
                                                u32* __restrict__ flags){
  __shared__ u16 wlds[96*512];
  const int wg  = blockIdx.x;
  const int tid = threadIdx.x;
  const bool isA = (wg < 16);
  u32* doneA = flags;
  u32* doneB = flags + 1024;

  // --- fill LDS weight slice (f32 -> f16, XOR-swizzled rows) ---
  {
    const int u0 = isA ? wg*32 : (wg-16)*16;
    for (int idx = tid; idx < 96*64; idx += 256){
      int lr = idx >> 6, k8 = idx & 63;
      const float* src;
      if (isA){
        int gate = lr >> 5, ul = lr & 31;
        src = Whh + ((size_t)(gate*512 + u0 + ul))*H + k8*8;       // layer 0 W_hh
      } else if (lr < 48){
        int gate = lr >> 4, ul = lr & 15;
        src = Wih + (size_t)G3*H + ((size_t)(gate*512 + u0 + ul))*H + k8*8;  // layer 1 W_ih
      } else {
        int lr2 = lr - 48; int gate = lr2 >> 4, ul = lr2 & 15;
        src = Whh + (size_t)G3*H + ((size_t)(gate*512 + u0 + ul))*H + k8*8;  // layer 1 W_hh
      }
      f16x8 v;
#pragma unroll
      for (int q=0;q<8;q++) v[q] = (_Float16)src[q];
      *(f16x8*)((char*)wlds + lr*1024 + ((k8*16) ^ ((lr&7)<<4))) = v;
    }
  }
  __syncthreads();

  const int wave = tid >> 6, lane = tid & 63;
  const int l15 = lane & 15, lk = lane >> 4;

  if (isA){
    // ----- layer 0: 4 waves, wave = (bm, ntg); owns 16 b x 16 u -----
    const int u0  = wg*32;
    const int bm  = wave >> 1, ntg = wave & 1;
    const int cu  = u0 + ntg*16 + l15;          // global hidden unit
    const float bhr = bhh[cu], bhu = bhh[512+cu], bhn = bhh[1024+cu];
    float hown[4];
#pragma unroll
    for (int j=0;j<4;j++) hown[j] = h0in[(size_t)(bm*16 + lk*4 + j)*H + cu];

    for (int t=0; t<T; t++){
      // prefetch gx0 (no dependency) before the spin
      float gxr[4], gxu[4], gxn[4];
#pragma unroll
      for (int j=0;j<4;j++){
        size_t base = ((size_t)t*B + (bm*16 + lk*4 + j))*G3;
        gxr[j] = h2f(gx0[base + cu]);
        gxu[j] = h2f(gx0[base + 512 + cu]);
        gxn[j] = h2f(gx0[base + 1024 + cu]);
      }
      if (t > 0) spin_ge(doneA + (t-1), 64);
      const u16* hprev = (t==0) ? h0i : (h0all + (size_t)(t-1)*(B*H));

      f32x4 aR{}, aU{}, aN{};
#pragma unroll
      for (int kk=0; kk<16; kk++){
        int k0 = kk*32 + lk*8;
        f16x8 af = *(const f16x8*)(hprev + (size_t)(bm*16 + l15)*H + k0);
        aR = MFMA16(af, lds_frag(wlds,      ntg*16, l15, lk, kk), aR);
        aU = MFMA16(af, lds_frag(wlds, 32 + ntg*16, l15, lk, kk), aU);
        aN = MFMA16(af, lds_frag(wlds, 64 + ntg*16, l15, lk, kk), aN);
      }
#pragma unroll
      for (int j=0;j<4;j++){
        float r = fsig(gxr[j] + aR[j] + bhr);
        float u = fsig(gxu[j] + aU[j] + bhu);
        float n = ftanh(gxn[j] + r*(aN[j] + bhn));
        hown[j] = u*hown[j] + (1.f-u)*n;
        coh_store_u16(h0all + (size_t)t*(B*H) + (size_t)(bm*16 + lk*4 + j)*H + cu,
                      (u32)f2h(hown[j]));
      }
      asm volatile("s_waitcnt vmcnt(0)" ::: "memory");
      if (lane == 0) coh_atomic_inc(doneA + t);
    }
  } else {
    // ----- layer 1: waves 0,1 work (bm = wave); owns 16 b x 16 u -----
    if (wave >= 2) return;
    const int u0 = (wg-16)*16;
    const int bm = wave;
    const int cu = u0 + l15;
    const float br  = bih[G3 + cu]        + bhh[G3 + cu];
    const float bu  = bih[G3 + 512 + cu]  + bhh[G3 + 512 + cu];
    const float bni = bih[G3 + 1024 + cu];
    const float bnh = bhh[G3 + 1024 + cu];
    float hown[4];
#pragma unroll
    for (int j=0;j<4;j++) hown[j] = h0in[(size_t)B*H + (size_t)(bm*16 + lk*4 + j)*H + cu];

    for (int t=0; t<T; t++){
      spin_ge(doneA + t, 64);
      if (t > 0) spin_ge(doneB + (t-1), 64);
      const u16* xsrc = h0all + (size_t)t*(B*H);
      const u16* hsrc = (t==0) ? h1i : (h1all + (size_t)(t-1)*(B*H));

      f32x4 xR{}, xU{}, xN{}, hR{}, hU{}, hN{};
#pragma unroll
      for (int kk=0; kk<16; kk++){
        int k0 = kk*32 + lk*8;
        size_t ro = (size_t)(bm*16 + l15)*H + k0;
        f16x8 ax = *(const f16x8*)(xsrc + ro);
        f16x8 ah = *(const f16x8*)(hsrc + ro);
        xR = MFMA16(ax, lds_frag(wlds,  0, l15, lk, kk), xR);
        xU = MFMA16(ax, lds_frag(wlds, 16, l15, lk, kk), xU);
        xN = MFMA16(ax, lds_frag(wlds, 32, l15, lk, kk), xN);
        hR = MFMA16(ah, lds_frag(wlds, 48, l15, lk, kk), hR);
        hU = MFMA16(ah, lds_frag(wlds, 64, l15, lk, kk), hU);
        hN = MFMA16(ah, lds_frag(wlds, 80, l15, lk, kk), hN);
      }
#pragma unroll
      for (int j=0;j<4;j++){
        float r = fsig(xR[j] + hR[j] + br);
        float u = fsig(xU[j] + hU[j] + bu);
        float n = ftanh(xN[j] + bni + r*(hN[j] + bnh));
        hown[j] = u*hown[j] + (1.f-u)*n;
        int b = bm*16 + lk*4 + j;
        coh_store_u16(h1all + (size_t)t*(B*H) + (size_t)b*H + cu, (u32)f2h(hown[j]));
        if (t == T-1) h1fin[(size_t)b*H + cu] = hown[j];
      }
      asm volatile("s_waitcnt vmcnt(0)" ::: "memory");
      if (lane == 0) coh_atomic_inc(doneB + t);
    }
  }
}

// ---------------- k3: FC ----------------
__global__ __launch_bounds__(256) void k3_fc(const float* __restrict__ h1fin,
                                             const float* __restrict__ fcW,
                                             const float* __restrict__ fcb,
                                             float* __restrict__ out){
  int g = blockIdx.x*256 + threadIdx.x;     // 16384
  int b = g >> 9, o = g & 511;
  const f32x4* w = (const f32x4*)(fcW + (size_t)o*H);
  const f32x4* h = (const f32x4*)(h1fin + (size_t)b*H);
  float acc = fcb[o];
#pragma unroll 4
  for (int k=0;k<128;k++){
    f32x4 wv = w[k], hv = h[k];
    acc += wv[0]*hv[0] + wv[1]*hv[1] + wv[2]*hv[2] + wv[3]*hv[3];
  }
  out[g] = acc;
}

extern "C" void kernel_launch(void* const* d_in, const int* in_sizes, int n_in,
                              void* d_out, int out_size, void* d_ws, size_t ws_size,
                              hipStream_t stream) {
  const float* x    = (const float*)d_in[0];
  const float* h0   = (const float*)d_in[1];
  const float* Wih  = (const float*)d_in[2];
  const float* bihv = (const float*)d_in[3];
  const float* Whh  = (const float*)d_in[4];
  const float* bhhv = (const float*)d_in[5];
  const float* fcW  = (const float*)d_in[6];
  const float* fcb  = (const float*)d_in[7];
  float* out = (float*)d_out;

  char* ws = (char*)d_ws;
  u16* gx0     = (u16*)(ws + OFF_GX0);
  u16* h0all   = (u16*)(ws + OFF_H0ALL);
  u16* h1all   = (u16*)(ws + OFF_H1ALL);
  u16* wih0f16 = (u16*)(ws + OFF_WIH0);
  u16* h0i     = (u16*)(ws + OFF_H0I);
  u16* h1i     = (u16*)(ws + OFF_H1I);
  float* h1fin = (float*)(ws + OFF_H1F);
  u32* flags   = (u32*)(ws + OFF_FLG);

  k0_prep<<<256, 256, 0, stream>>>(Wih, h0, wih0f16, h0i, h1i, flags);
  k1_gx<<<T*6, 256, 0, stream>>>(x, wih0f16, bihv, gx0);
  k2_recur<<<48, 256, 0, stream>>>(h0, Wih, bihv, Whh, bhhv,
                                   gx0, h0all, h1all, h0i, h1i, h1fin, flags);
  k3_fc<<<64, 256, 0, stream>>>(h1fin, fcW, fcb, out);
}

// Round 2
// 6382.278 us; speedup vs baseline: 1.1205x; 1.1205x over previous
//
#include <hip/hip_runtime.h>
#include <hip/hip_bf16.h>

// GRU: L=2, B=32, T=1024, H=512, OUT=512
// Round 2: atomic-free canary sync (per-wave flag word, coalesced 64-wide poll),
// layer-1 x-side matmul moved off the serial spine, coherent dwordx4 h-reads
// with split vmcnt, gx0 repacked [t][gate][u][b].

typedef _Float16 f16x8 __attribute__((ext_vector_type(8)));
typedef float f32x4 __attribute__((ext_vector_type(4)));
typedef unsigned short u16;
typedef unsigned int u32;
typedef u32 u32x2 __attribute__((ext_vector_type(2)));

#define MFMA16(a,b,c) __builtin_amdgcn_mfma_f32_16x16x32_f16((a),(b),(c),0,0,0)
#define SB0 __builtin_amdgcn_sched_barrier(0)

static constexpr int B = 32, T = 1024, H = 512, G3 = 1536;

// ws layout (bytes)
static constexpr size_t OFF_GX0   = 0;                                  // 96MB   [t][gate][u][b] f16
static constexpr size_t OFF_H0ALL = OFF_GX0   + (size_t)T*B*G3*2;       // 32MB   [t][b][u] f16
static constexpr size_t OFF_H1ALL = OFF_H0ALL + (size_t)T*B*H*2;        // 32MB
static constexpr size_t OFF_WIH0  = OFF_H1ALL + (size_t)T*B*H*2;        // 1.5MB
static constexpr size_t OFF_H0I   = OFF_WIH0  + (size_t)G3*H*2;
static constexpr size_t OFF_H1I   = OFF_H0I   + (size_t)B*H*2;
static constexpr size_t OFF_H1F   = OFF_H1I   + (size_t)B*H*2;          // f32
static constexpr size_t OFF_FLG   = OFF_H1F   + (size_t)B*H*4;          // canaryA[1024][64], canaryB[1024][64] u32

__device__ __forceinline__ u16 f2h(float x){ _Float16 h=(_Float16)x; return __builtin_bit_cast(u16,h); }
__device__ __forceinline__ float h2f(u16 u){ _Float16 h=__builtin_bit_cast(_Float16,u); return (float)h; }

// ---- coherent (device-scope, LLC) primitives ----
__device__ __forceinline__ u32 coh_load_u32(const u32* p){
  u32 r;
  asm volatile("global_load_dword %0, %1, off sc0 sc1\n\ts_waitcnt vmcnt(0)"
               : "=v"(r) : "v"(p) : "memory");
  return r;
}
__device__ __forceinline__ f16x8 coh_load16(const u16* p){   // NO waitcnt inside
  f16x8 r;
  asm volatile("global_load_dwordx4 %0, %1, off sc0 sc1" : "=v"(r) : "v"(p));
  return r;
}
__device__ __forceinline__ void coh_store_u16(u16* p, u32 v){
  asm volatile("global_store_short %0, %1, off sc0 sc1" :: "v"(p), "v"(v) : "memory");
}
__device__ __forceinline__ void coh_store_u32(u32* p, u32 v){
  asm volatile("global_store_dword %0, %1, off sc0 sc1" :: "v"(p), "v"(v) : "memory");
}
#define VMWAIT8 asm volatile("s_waitcnt vmcnt(8)" ::: "memory")
#define VMWAIT0 asm volatile("s_waitcnt vmcnt(0)" ::: "memory")

// poll 64 per-wave canaries in one coalesced 256B coherent read
__device__ __forceinline__ void poll64(const u32* base, u32 want, int lane){
  const u32* p = base + lane;
  while (!__all(coh_load_u32(p) == want)) {}
}

__device__ __forceinline__ float fsig(float x){ return 1.f/(1.f+__expf(-x)); }
__device__ __forceinline__ float ftanh(float x){
  x = fminf(15.f, fmaxf(-15.f, x));
  float e = __expf(-2.f*x);
  return (1.f-e)/(1.f+e);
}

// MFMA B-operand fragment from XOR-swizzled LDS weights [96 rows][512] f16
__device__ __forceinline__ f16x8 lds_frag(const u16* wlds, int lrbase, int l15, int lk, int kk){
  int lr = lrbase + l15;
  int byte = lr*1024 + (((((kk<<5)+(lk<<3))<<1)) ^ ((lr&7)<<4));
  return *(const f16x8*)((const char*)wlds + byte);
}

__device__ __forceinline__ float gxval(u32x2 g, int j){
  u32 w = (j & 2) ? g[1] : g[0];
  return h2f((u16)(w >> ((j & 1) * 16)));
}

// ---------------- k0: prep ----------------
__global__ __launch_bounds__(256) void k0_prep(const float* __restrict__ wih,
                                               const float* __restrict__ h0in,
                                               u16* __restrict__ wih0f16,
                                               u16* __restrict__ h0i,
                                               u16* __restrict__ h1i,
                                               u32* __restrict__ flags){
  int i = blockIdx.x*256 + threadIdx.x;                   // 65536 threads
  for (int idx=i; idx < G3*H; idx += 65536) wih0f16[idx] = f2h(wih[idx]);
  flags[i] = 0; flags[i + 65536] = 0;                     // canaryA + canaryB
  if (i < B*H){ h0i[i] = f2h(h0in[i]); h1i[i] = f2h(h0in[B*H + i]); }
}

// ---------------- k1: gx0 GEMM  (out layout [t][gate][u][b] f16) ----------------
__global__ __launch_bounds__(256) void k1_gx(const float* __restrict__ x,
                                             const u16* __restrict__ wih0,
                                             const float* __restrict__ bih0,
                                             u16* __restrict__ gxT){
  int t  = blockIdx.x / 6, nb = blockIdx.x % 6;
  int wave = threadIdx.x >> 6, lane = threadIdx.x & 63;
  int l15 = lane & 15, lk = lane >> 4;
  int colbase = nb*256 + wave*64;
  f32x4 acc[2][4] = {};
#pragma unroll 4
  for (int kk=0; kk<16; kk++){
    int k0 = kk*32 + lk*8;
    f16x8 a[2];
#pragma unroll
    for (int bm=0; bm<2; bm++){
      const f32x4* xp = (const f32x4*)(x + ((size_t)(bm*16+l15)*T + t)*H + k0);
      f32x4 x0 = xp[0], x1 = xp[1];
      f16x8 v;
#pragma unroll
      for (int q=0;q<4;q++){ v[q] = (_Float16)x0[q]; v[4+q] = (_Float16)x1[q]; }
      a[bm] = v;
    }
#pragma unroll
    for (int nt=0; nt<4; nt++){
      int col = colbase + nt*16 + l15;
      f16x8 bf = *(const f16x8*)(wih0 + (size_t)col*H + k0);
      acc[0][nt] = MFMA16(a[0], bf, acc[0][nt]);
      acc[1][nt] = MFMA16(a[1], bf, acc[1][nt]);
    }
  }
#pragma unroll
  for (int nt=0; nt<4; nt++){
    int col = colbase + nt*16 + l15;
    float bias = bih0[col];
#pragma unroll
    for (int bm=0; bm<2; bm++){
      u32 lo = (u32)f2h(acc[bm][nt][0]+bias) | ((u32)f2h(acc[bm][nt][1]+bias) << 16);
      u32 hi = (u32)f2h(acc[bm][nt][2]+bias) | ((u32)f2h(acc[bm][nt][3]+bias) << 16);
      u32x2 v; v[0] = lo; v[1] = hi;
      *(u32x2*)(gxT + ((size_t)t*G3 + col)*B + bm*16 + lk*4) = v;
    }
  }
}

// ---------------- k2: persistent recurrence ----------------
__global__ __launch_bounds__(256,1) void k2_recur(const float* __restrict__ h0in,
                                                  const float* __restrict__ Wih,
                                                  const float* __restrict__ bih,
                                                  const float* __restrict__ Whh,
                                                  const float* __restrict__ bhh,
                                                  const u16* __restrict__ gxT,
                                                  u16* __restrict__ h0all,
                                                  u16* __restrict__ h1all,
                                                  const u16* __restrict__ h0i,
                                                  const u16* __restrict__ h1i,
                                                  float* __restrict__ h1fin,
                                                  u32* __restrict__ flags){
  __shared__ u16 wlds[96*512];
  const int wg  = blockIdx.x;
  const int tid = threadIdx.x;
  const bool isA = (wg < 16);
  u32* canA = flags;               // [t][64]
  u32* canB = flags + (size_t)64*1024;

  // --- fill LDS weight slice (f32 -> f16, XOR-swizzled rows) ---
  {
    const int u0 = isA ? wg*32 : (wg-16)*16;
    for (int idx = tid; idx < 96*64; idx += 256){
      int lr = idx >> 6, k8 = idx & 63;
      const float* src;
      if (isA){
        int gate = lr >> 5, ul = lr & 31;
        src = Whh + ((size_t)(gate*512 + u0 + ul))*H + k8*8;                 // layer 0 W_hh
      } else if (lr < 48){
        int gate = lr >> 4, ul = lr & 15;
        src = Wih + (size_t)G3*H + ((size_t)(gate*512 + u0 + ul))*H + k8*8;  // layer 1 W_ih
      } else {
        int lr2 = lr - 48; int gate = lr2 >> 4, ul = lr2 & 15;
        src = Whh + (size_t)G3*H + ((size_t)(gate*512 + u0 + ul))*H + k8*8;  // layer 1 W_hh
      }
      f16x8 v;
#pragma unroll
      for (int q=0;q<8;q++) v[q] = (_Float16)src[q];
      *(f16x8*)((char*)wlds + lr*1024 + ((k8*16) ^ ((lr&7)<<4))) = v;
    }
  }
  __syncthreads();

  const int wave = tid >> 6, lane = tid & 63;
  const int l15 = lane & 15, lk = lane >> 4;

  if (isA){
    // ----- layer 0: 4 waves, wave = (bm, ntg); owns 16 b x 16 u -----
    const int u0  = wg*32;
    const int bm  = wave >> 1, ntg = wave & 1;
    const int cu  = u0 + ntg*16 + l15;
    const int waveid = wg*4 + wave;
    const float bhr = bhh[cu], bhu = bhh[512+cu], bhn = bhh[1024+cu];
    float hown[4];
#pragma unroll
    for (int j=0;j<4;j++) hown[j] = h0in[(size_t)(bm*16 + lk*4 + j)*H + cu];

    for (int t=0; t<T; t++){
      // prefetch gx (independent of the spin) — 3 x 8B
      const u16* gp = gxT + ((size_t)t*G3 + cu)*B + bm*16 + lk*4;
      u32x2 g0 = *(const u32x2*)gp;
      u32x2 g1 = *(const u32x2*)(gp + (size_t)512*B);
      u32x2 g2 = *(const u32x2*)(gp + (size_t)1024*B);

      if (t > 0) poll64(canA + (size_t)(t-1)*64, (u32)t, lane);
      const u16* hprev = (t==0) ? h0i : (h0all + (size_t)(t-1)*(B*H));
      const u16* hrow  = hprev + (size_t)(bm*16 + l15)*H + lk*8;

      f16x8 af[16];
#pragma unroll
      for (int kk=0; kk<16; kk++) af[kk] = coh_load16(hrow + kk*32);
      VMWAIT8; SB0;
      f32x4 aR{}, aU{}, aN{};
#pragma unroll
      for (int kk=0; kk<8; kk++){
        aR = MFMA16(af[kk], lds_frag(wlds,      ntg*16, l15, lk, kk), aR);
        aU = MFMA16(af[kk], lds_frag(wlds, 32 + ntg*16, l15, lk, kk), aU);
        aN = MFMA16(af[kk], lds_frag(wlds, 64 + ntg*16, l15, lk, kk), aN);
      }
      VMWAIT0; SB0;
#pragma unroll
      for (int kk=8; kk<16; kk++){
        aR = MFMA16(af[kk], lds_frag(wlds,      ntg*16, l15, lk, kk), aR);
        aU = MFMA16(af[kk], lds_frag(wlds, 32 + ntg*16, l15, lk, kk), aU);
        aN = MFMA16(af[kk], lds_frag(wlds, 64 + ntg*16, l15, lk, kk), aN);
      }
#pragma unroll
      for (int j=0;j<4;j++){
        float r = fsig(gxval(g0,j) + aR[j] + bhr);
        float u = fsig(gxval(g1,j) + aU[j] + bhu);
        float n = ftanh(gxval(g2,j) + r*(aN[j] + bhn));
        hown[j] = u*hown[j] + (1.f-u)*n;
        coh_store_u16(h0all + (size_t)t*(B*H) + (size_t)(bm*16 + lk*4 + j)*H + cu,
                      (u32)f2h(hown[j]));
      }
      VMWAIT0;
      if (lane == 0) coh_store_u32(canA + (size_t)t*64 + waveid, (u32)(t+1));
    }
  } else {
    // ----- layer 1: waves 0,1 work; x-side matmul off the spine -----
    if (wave >= 2) return;
    const int wg2 = wg - 16;
    const int u0 = wg2*16;
    const int bm = wave;
    const int cu = u0 + l15;
    const int waveid = wg2*2 + wave;
    const float br  = bih[G3 + cu]        + bhh[G3 + cu];
    const float bu  = bih[G3 + 512 + cu]  + bhh[G3 + 512 + cu];
    const float bni = bih[G3 + 1024 + cu];
    const float bnh = bhh[G3 + 1024 + cu];
    float hown[4];
#pragma unroll
    for (int j=0;j<4;j++) hown[j] = h0in[(size_t)B*H + (size_t)(bm*16 + lk*4 + j)*H + cu];

    for (int t=0; t<T; t++){
      // --- x-side: only needs h0(t); A runs ahead so this poll is short ---
      poll64(canA + (size_t)t*64, (u32)(t+1), lane);
      const u16* xrow = h0all + (size_t)t*(B*H) + (size_t)(bm*16 + l15)*H + lk*8;
      f16x8 ax[16];
#pragma unroll
      for (int kk=0; kk<16; kk++) ax[kk] = coh_load16(xrow + kk*32);
      VMWAIT8; SB0;
      f32x4 xR{}, xU{}, xN{};
#pragma unroll
      for (int kk=0; kk<8; kk++){
        xR = MFMA16(ax[kk], lds_frag(wlds,  0, l15, lk, kk), xR);
        xU = MFMA16(ax[kk], lds_frag(wlds, 16, l15, lk, kk), xU);
        xN = MFMA16(ax[kk], lds_frag(wlds, 32, l15, lk, kk), xN);
      }
      VMWAIT0; SB0;
#pragma unroll
      for (int kk=8; kk<16; kk++){
        xR = MFMA16(ax[kk], lds_frag(wlds,  0, l15, lk, kk), xR);
        xU = MFMA16(ax[kk], lds_frag(wlds, 16, l15, lk, kk), xU);
        xN = MFMA16(ax[kk], lds_frag(wlds, 32, l15, lk, kk), xN);
      }

      // --- h-side: the serial spine ---
      if (t > 0) poll64(canB + (size_t)(t-1)*64, (u32)t, lane);
      const u16* hsrc = (t==0) ? h1i : (h1all + (size_t)(t-1)*(B*H));
      const u16* hrow = hsrc + (size_t)(bm*16 + l15)*H + lk*8;
      f16x8 ah[16];
#pragma unroll
      for (int kk=0; kk<16; kk++) ah[kk] = coh_load16(hrow + kk*32);
      VMWAIT8; SB0;
      f32x4 hR{}, hU{}, hN{};
#pragma unroll
      for (int kk=0; kk<8; kk++){
        hR = MFMA16(ah[kk], lds_frag(wlds, 48, l15, lk, kk), hR);
        hU = MFMA16(ah[kk], lds_frag(wlds, 64, l15, lk, kk), hU);
        hN = MFMA16(ah[kk], lds_frag(wlds, 80, l15, lk, kk), hN);
      }
      VMWAIT0; SB0;
#pragma unroll
      for (int kk=8; kk<16; kk++){
        hR = MFMA16(ah[kk], lds_frag(wlds, 48, l15, lk, kk), hR);
        hU = MFMA16(ah[kk], lds_frag(wlds, 64, l15, lk, kk), hU);
        hN = MFMA16(ah[kk], lds_frag(wlds, 80, l15, lk, kk), hN);
      }
#pragma unroll
      for (int j=0;j<4;j++){
        float r = fsig(xR[j] + hR[j] + br);
        float u = fsig(xU[j] + hU[j] + bu);
        float n = ftanh(xN[j] + bni + r*(hN[j] + bnh));
        hown[j] = u*hown[j] + (1.f-u)*n;
        int b = bm*16 + lk*4 + j;
        coh_store_u16(h1all + (size_t)t*(B*H) + (size_t)b*H + cu, (u32)f2h(hown[j]));
        if (t == T-1) h1fin[(size_t)b*H + cu] = hown[j];
      }
      VMWAIT0;
      if (lane == 0) coh_store_u32(canB + (size_t)t*64 + waveid, (u32)(t+1));
    }
  }
}

// ---------------- k3: FC ----------------
__global__ __launch_bounds__(256) void k3_fc(const float* __restrict__ h1fin,
                                             const float* __restrict__ fcW,
                                             const float* __restrict__ fcb,
                                             float* __restrict__ out){
  int g = blockIdx.x*256 + threadIdx.x;     // 16384
  int b = g >> 9, o = g & 511;
  const f32x4* w = (const f32x4*)(fcW + (size_t)o*H);
  const f32x4* h = (const f32x4*)(h1fin + (size_t)b*H);
  float acc = fcb[o];
#pragma unroll 4
  for (int k=0;k<128;k++){
    f32x4 wv = w[k], hv = h[k];
    acc += wv[0]*hv[0] + wv[1]*hv[1] + wv[2]*hv[2] + wv[3]*hv[3];
  }
  out[g] = acc;
}

extern "C" void kernel_launch(void* const* d_in, const int* in_sizes, int n_in,
                              void* d_out, int out_size, void* d_ws, size_t ws_size,
                              hipStream_t stream) {
  const float* x    = (const float*)d_in[0];
  const float* h0   = (const float*)d_in[1];
  const float* Wih  = (const float*)d_in[2];
  const float* bihv = (const float*)d_in[3];
  const float* Whh  = (const float*)d_in[4];
  const float* bhhv = (const float*)d_in[5];
  const float* fcW  = (const float*)d_in[6];
  const float* fcb  = (const float*)d_in[7];
  float* out = (float*)d_out;

  char* ws = (char*)d_ws;
  u16* gxT     = (u16*)(ws + OFF_GX0);
  u16* h0all   = (u16*)(ws + OFF_H0ALL);
  u16* h1all   = (u16*)(ws + OFF_H1ALL);
  u16* wih0f16 = (u16*)(ws + OFF_WIH0);
  u16* h0i     = (u16*)(ws + OFF_H0I);
  u16* h1i     = (u16*)(ws + OFF_H1I);
  float* h1fin = (float*)(ws + OFF_H1F);
  u32* flags   = (u32*)(ws + OFF_FLG);

  k0_prep<<<256, 256, 0, stream>>>(Wih, h0, wih0f16, h0i, h1i, flags);
  k1_gx<<<T*6, 256, 0, stream>>>(x, wih0f16, bihv, gxT);
  k2_recur<<<48, 256, 0, stream>>>(h0, Wih, bihv, Whh, bhhv,
                                   gxT, h0all, h1all, h0i, h1i, h1fin, flags);
  k3_fc<<<64, 256, 0, stream>>>(h1fin, fcW, fcb, out);
}